// Round 6
// baseline (410.801 us; speedup 1.0000x reference)
//
#include <hip/hip_runtime.h>

#define D 32
#define RANGE 400        // nodes per dst-range; agg tile = 400*32*4B = 50KB LDS
#define RMAX 512         // LDS counter capacity (R = ceil(n/RANGE) = 250)
#define JC 512           // edge chunks for count/reorder passes
#define SCAN_CHUNK 4096  // scan: 256 threads x 16 elems

// ---- K1: per-(range,chunk) counts for dst AND src in one pass. ----
__global__ void count_kernel(const int* __restrict__ src, const int* __restrict__ dst,
                             int* __restrict__ cnt, int E, int R, int chunk) {
    __shared__ int cd[RMAX];
    __shared__ int cs[RMAX];
    int j = blockIdx.x;
    for (int i = threadIdx.x; i < R; i += blockDim.x) { cd[i] = 0; cs[i] = 0; }
    __syncthreads();
    int e0 = j * chunk, e1 = min(E, e0 + chunk);
    for (int e = e0 + threadIdx.x; e < e1; e += blockDim.x) {
        atomicAdd(&cd[dst[e] / RANGE], 1);
        atomicAdd(&cs[src[e] / RANGE], 1);
    }
    __syncthreads();
    // layout: cnt[r*JC + j] (dst) ; cnt[(R+r)*JC + j] (src)
    for (int i = threadIdx.x; i < R; i += blockDim.x) {
        cnt[(size_t)i * JC + j]       = cd[i];
        cnt[(size_t)(R + i) * JC + j] = cs[i];
    }
}

// ---- hierarchical exclusive scan over 2*R*JC counts ----
__global__ void scan_part(const int* __restrict__ deg, int* __restrict__ offsets,
                          int* __restrict__ blockSums, int n) {
    __shared__ int lds[256];
    int t = threadIdx.x;
    int base = blockIdx.x * SCAN_CHUNK + t * 16;
    int v[16];
    int tsum = 0;
#pragma unroll
    for (int i = 0; i < 16; i++) {
        int idx = base + i;
        int x = (idx < n) ? deg[idx] : 0;
        v[i] = tsum;
        tsum += x;
    }
    lds[t] = tsum;
    __syncthreads();
    for (int off = 1; off < 256; off <<= 1) {
        int val = (t >= off) ? lds[t - off] : 0;
        __syncthreads();
        lds[t] += val;
        __syncthreads();
    }
    int texcl = (t == 0) ? 0 : lds[t - 1];
    if (t == 255) blockSums[blockIdx.x] = lds[255];
#pragma unroll
    for (int i = 0; i < 16; i++) {
        int idx = base + i;
        if (idx < n) offsets[idx] = texcl + v[i];
    }
}

__global__ void scan_top(int* __restrict__ blockSums, int nb) {
    __shared__ int lds[64];
    int t = threadIdx.x;
    lds[t] = (t < nb) ? blockSums[t] : 0;
    __syncthreads();
    for (int off = 1; off < 64; off <<= 1) {
        int val = (t >= off) ? lds[t - off] : 0;
        __syncthreads();
        lds[t] += val;
        __syncthreads();
    }
    if (t < nb) blockSums[t] = (t == 0) ? 0 : lds[t - 1];
}

__global__ void scan_add(int* __restrict__ offsets, const int* __restrict__ blockSums, int n) {
    int i = blockIdx.x * blockDim.x + threadIdx.x;
    if (i < n) offsets[i] += blockSums[i / SCAN_CHUNK];
}

// ---- K2s: reorder src values into src-range buckets (4B records). ----
// recsS_m is pre-offset by -E so src-bucket offsets in [E,2E) index [0,E).
__global__ void reorder_src(const int* __restrict__ src, const int* __restrict__ offs,
                            unsigned int* __restrict__ recsS_m, int E, int R, int chunk) {
    __shared__ int cur[RMAX];
    int j = blockIdx.x;
    for (int i = threadIdx.x; i < R; i += blockDim.x) cur[i] = offs[(size_t)(R + i) * JC + j];
    __syncthreads();
    int e0 = j * chunk, e1 = min(E, e0 + chunk);
    for (int e = e0 + threadIdx.x; e < e1; e += blockDim.x) {
        int s = src[e];
        int pos = atomicAdd(&cur[s / RANGE], 1);  // LDS atomic
        recsS_m[pos] = (unsigned)s;
    }
}

// ---- K3s: per-node out-degree count in LDS -> src_norm. ----
__global__ void srcnorm_kernel(const unsigned int* __restrict__ recsS_m,
                               const int* __restrict__ offs, float* __restrict__ src_norm,
                               int E, int n, int R) {
    __shared__ int cnt[RANGE];
    int r = blockIdx.x;
    int base = r * RANGE;
    int lim = min(n - base, RANGE);
    for (int i = threadIdx.x; i < RANGE; i += blockDim.x) cnt[i] = 0;
    __syncthreads();
    int start = offs[(size_t)(R + r) * JC];
    int end = (r + 1 < R) ? offs[(size_t)(R + r + 1) * JC] : 2 * E;
    for (int i = start + threadIdx.x; i < end; i += blockDim.x)
        atomicAdd(&cnt[recsS_m[i] - base], 1);
    __syncthreads();
    for (int i = threadIdx.x; i < lim; i += blockDim.x)
        src_norm[base + i] = rsqrtf((float)max(cnt[i], 1));
}

// ---- K4: fp32 -> bf16 feature table (RNE). Runs after K3s (aliases recsS). ----
__device__ __forceinline__ unsigned short f2bf(float x) {
    unsigned u = __float_as_uint(x);
    u += 0x7FFFu + ((u >> 16) & 1u);
    return (unsigned short)(u >> 16);
}

__global__ void convert_kernel(const float* __restrict__ feat, unsigned short* __restrict__ featb,
                               int total4) {
    int i = blockIdx.x * blockDim.x + threadIdx.x;
    if (i >= total4) return;
    float4 f = ((const float4*)feat)[i];
    ushort4 u;
    u.x = f2bf(f.x); u.y = f2bf(f.y); u.z = f2bf(f.z); u.w = f2bf(f.w);
    ((ushort4*)featb)[i] = u;
}

// ---- K2d: reorder edges into dst-range buckets; weight folded. 8B records. ----
// rec.x = s | d_local<<17 ; rec.y = w bits (0 for self-loop)
__global__ void reorder_dst(const int* __restrict__ src, const int* __restrict__ dst,
                            const float* __restrict__ ef, const float* __restrict__ src_norm,
                            const int* __restrict__ offs, uint2* __restrict__ recs,
                            int E, int R, int chunk) {
    __shared__ int cur[RMAX];
    int j = blockIdx.x;
    for (int i = threadIdx.x; i < R; i += blockDim.x) cur[i] = offs[(size_t)i * JC + j];
    __syncthreads();
    int e0 = j * chunk, e1 = min(E, e0 + chunk);
    for (int e = e0 + threadIdx.x; e < e1; e += blockDim.x) {
        int s = src[e], d = dst[e];
        int r = d / RANGE;
        int dl = d - r * RANGE;
        float w = (s == d) ? 0.0f : ef[e] * src_norm[s];
        int pos = atomicAdd(&cur[r], 1);  // LDS atomic
        recs[pos] = make_uint2((unsigned)s | ((unsigned)dl << 17), __float_as_uint(w));
    }
}

// ---- K3d: fused gather + LDS aggregation + output. One block per range. ----
__global__ __launch_bounds__(1024) void gather_kernel(
        const float* __restrict__ feat, const unsigned short* __restrict__ featb,
        const uint2* __restrict__ recs, const int* __restrict__ offs,
        float* __restrict__ out, int E, int n, int R) {
    __shared__ float agg[RANGE * D];   // 50 KB
    __shared__ int indeg[RANGE];
    int r = blockIdx.x;
    int base = r * RANGE;
    int lim = min(n - base, RANGE);
    for (int i = threadIdx.x; i < RANGE * D; i += blockDim.x) agg[i] = 0.0f;
    for (int i = threadIdx.x; i < RANGE; i += blockDim.x) indeg[i] = 0;
    __syncthreads();
    int start = offs[(size_t)r * JC];
    int end = (r + 1 < R) ? offs[(size_t)(r + 1) * JC] : E;
    int g = threadIdx.x >> 3;   // 128 edge groups
    int c = threadIdx.x & 7;    // 8 lanes x 4 floats = 32
    for (int i = start + g; i < end; i += 128) {
        uint2 rec = recs[i];
        unsigned s = rec.x & 0x1FFFFu;
        int dl = (int)((rec.x >> 17) & 0x1FFu);
        float w = __uint_as_float(rec.y);
        if (c == 0) atomicAdd(&indeg[dl], 1);
        uint2 b = ((const uint2*)(featb + (size_t)s * D))[c];
        float* a = &agg[dl * D + c * 4];
        atomicAdd(a + 0, __uint_as_float(b.x << 16) * w);
        atomicAdd(a + 1, __uint_as_float(b.x & 0xFFFF0000u) * w);
        atomicAdd(a + 2, __uint_as_float(b.y << 16) * w);
        atomicAdd(a + 3, __uint_as_float(b.y & 0xFFFF0000u) * w);
    }
    __syncthreads();
    for (int node = g; node < lim; node += 128) {
        float dn = rsqrtf((float)max(indeg[node], 1));
        float4 f = ((const float4*)(feat + (size_t)(base + node) * D))[c];
        float4 a = ((const float4*)&agg[node * D])[c];
        float v = fabsf(f.x - a.x * dn) + fabsf(f.y - a.y * dn) +
                  fabsf(f.z - a.z * dn) + fabsf(f.w - a.w * dn);
        v += __shfl_xor(v, 1, 8);
        v += __shfl_xor(v, 2, 8);
        v += __shfl_xor(v, 4, 8);
        if (c == 0) out[base + node] = v;
    }
}

extern "C" void kernel_launch(void* const* d_in, const int* in_sizes, int n_in,
                              void* d_out, int out_size, void* d_ws, size_t ws_size,
                              hipStream_t stream) {
    const float* feat   = (const float*)d_in[0];
    const float* e_feat = (const float*)d_in[1];
    const int*   src    = (const int*)d_in[2];
    const int*   dst    = (const int*)d_in[3];
    const int E = in_sizes[2];
    const int n = in_sizes[0] / D;
    float* out = (float*)d_out;

    const int R = (n + RANGE - 1) / RANGE;   // 250
    const int chunk = (E + JC - 1) / JC;     // 3125
    const int total = 2 * R * JC;            // 256000 counts

    // ws layout (all offsets 16B-aligned):
    //   cnt[total] int | offs[total] int | blockSums[64] int | src_norm[n] float |
    //   recs_d[E] uint2 | featb[n*D] ushort (aliases recsS[E] uint — recsS dead after K3s)
    char* p = (char*)d_ws;
    int* cnt       = (int*)p;                 p += ((size_t)total * 4 + 15) & ~(size_t)15;
    int* offs      = (int*)p;                 p += ((size_t)total * 4 + 15) & ~(size_t)15;
    int* blockSums = (int*)p;                 p += 64 * 4;
    float* src_norm = (float*)p;              p += ((size_t)n * 4 + 15) & ~(size_t)15;
    uint2* recs    = (uint2*)p;               p += ((size_t)E * 8 + 15) & ~(size_t)15;
    unsigned short* featb = (unsigned short*)p;
    unsigned int* recsS_m = (unsigned int*)featb - (size_t)E;  // index with [E, 2E)

    count_kernel<<<JC, 256, 0, stream>>>(src, dst, cnt, E, R, chunk);

    int nb = (total + SCAN_CHUNK - 1) / SCAN_CHUNK;  // 63 (<=64)
    scan_part<<<nb, 256, 0, stream>>>(cnt, offs, blockSums, total);
    scan_top<<<1, 64, 0, stream>>>(blockSums, nb);
    scan_add<<<(total + 255) / 256, 256, 0, stream>>>(offs, blockSums, total);

    reorder_src<<<JC, 256, 0, stream>>>(src, offs, recsS_m, E, R, chunk);
    srcnorm_kernel<<<R, 256, 0, stream>>>(recsS_m, offs, src_norm, E, n, R);

    int total4 = n * D / 4;
    convert_kernel<<<(total4 + 255) / 256, 256, 0, stream>>>(feat, featb, total4);

    reorder_dst<<<JC, 256, 0, stream>>>(src, dst, e_feat, src_norm, offs, recs, E, R, chunk);

    gather_kernel<<<R, 1024, 0, stream>>>(feat, featb, recs, offs, out, E, n, R);
}

// Round 7
// 176.932 us; speedup vs baseline: 2.3218x; 2.3218x over previous
//
#include <hip/hip_runtime.h>

#define D 32
#define RANGE 128        // nodes per range; R = ceil(n/RANGE) = 782
#define RMAX 800         // LDS counter capacity for coarse passes
#define JC 512           // edge chunks for count/reorder passes
#define SCAN_CHUNK 4096  // scan: 256 threads x 16 elems
#define CAP 2560         // LDS sorted-record capacity per range (mean 2048, +11 sigma)

// ---- K1: per-(range,chunk) coarse counts for dst AND src in one pass. ----
__global__ void count_kernel(const int* __restrict__ src, const int* __restrict__ dst,
                             int* __restrict__ cnt, int E, int R, int chunk) {
    __shared__ int cd[RMAX];
    __shared__ int cs[RMAX];
    int j = blockIdx.x;
    for (int i = threadIdx.x; i < R; i += blockDim.x) { cd[i] = 0; cs[i] = 0; }
    __syncthreads();
    int e0 = j * chunk, e1 = min(E, e0 + chunk);
    for (int e = e0 + threadIdx.x; e < e1; e += blockDim.x) {
        atomicAdd(&cd[dst[e] >> 7], 1);   // RANGE = 128
        atomicAdd(&cs[src[e] >> 7], 1);
    }
    __syncthreads();
    // layout: cnt[r*JC + j] (dst) ; cnt[(R+r)*JC + j] (src)
    for (int i = threadIdx.x; i < R; i += blockDim.x) {
        cnt[(size_t)i * JC + j]       = cd[i];
        cnt[(size_t)(R + i) * JC + j] = cs[i];
    }
}

// ---- hierarchical exclusive scan over 2*R*JC counts ----
__global__ void scan_part(const int* __restrict__ deg, int* __restrict__ offsets,
                          int* __restrict__ blockSums, int n) {
    __shared__ int lds[256];
    int t = threadIdx.x;
    int base = blockIdx.x * SCAN_CHUNK + t * 16;
    int v[16];
    int tsum = 0;
#pragma unroll
    for (int i = 0; i < 16; i++) {
        int idx = base + i;
        int x = (idx < n) ? deg[idx] : 0;
        v[i] = tsum;
        tsum += x;
    }
    lds[t] = tsum;
    __syncthreads();
    for (int off = 1; off < 256; off <<= 1) {
        int val = (t >= off) ? lds[t - off] : 0;
        __syncthreads();
        lds[t] += val;
        __syncthreads();
    }
    int texcl = (t == 0) ? 0 : lds[t - 1];
    if (t == 255) blockSums[blockIdx.x] = lds[255];
#pragma unroll
    for (int i = 0; i < 16; i++) {
        int idx = base + i;
        if (idx < n) offsets[idx] = texcl + v[i];
    }
}

__global__ void scan_top(int* __restrict__ blockSums, int nb) {
    __shared__ int lds[256];
    int t = threadIdx.x;
    lds[t] = (t < nb) ? blockSums[t] : 0;
    __syncthreads();
    for (int off = 1; off < 256; off <<= 1) {
        int val = (t >= off) ? lds[t - off] : 0;
        __syncthreads();
        lds[t] += val;
        __syncthreads();
    }
    if (t < nb) blockSums[t] = (t == 0) ? 0 : lds[t - 1];
}

__global__ void scan_add(int* __restrict__ offsets, const int* __restrict__ blockSums, int n) {
    int i = blockIdx.x * blockDim.x + threadIdx.x;
    if (i < n) offsets[i] += blockSums[i / SCAN_CHUNK];
}

// ---- K2s: reorder src ids into src-range buckets (4B records). ----
// recsS_m is pre-offset by -E so src-bucket offsets in [E,2E) index [0,E).
__global__ void reorder_src(const int* __restrict__ src, const int* __restrict__ offs,
                            unsigned int* __restrict__ recsS_m, int E, int R, int chunk) {
    __shared__ int cur[RMAX];
    int j = blockIdx.x;
    for (int i = threadIdx.x; i < R; i += blockDim.x) cur[i] = offs[(size_t)(R + i) * JC + j];
    __syncthreads();
    int e0 = j * chunk, e1 = min(E, e0 + chunk);
    for (int e = e0 + threadIdx.x; e < e1; e += blockDim.x) {
        int s = src[e];
        int pos = atomicAdd(&cur[s >> 7], 1);  // LDS atomic
        recsS_m[pos] = (unsigned)s;
    }
}

// ---- K3s: per-node out-degree count in LDS -> src_norm. ----
__global__ void srcnorm_kernel(const unsigned int* __restrict__ recsS_m,
                               const int* __restrict__ offs, float* __restrict__ src_norm,
                               int E, int n, int R) {
    __shared__ int cnt[RANGE];
    int r = blockIdx.x;
    int base = r * RANGE;
    int lim = min(n - base, RANGE);
    for (int i = threadIdx.x; i < RANGE; i += blockDim.x) cnt[i] = 0;
    __syncthreads();
    int start = offs[(size_t)(R + r) * JC];
    int end = (r + 1 < R) ? offs[(size_t)(R + r + 1) * JC] : 2 * E;
    for (int i = start + threadIdx.x; i < end; i += blockDim.x)
        atomicAdd(&cnt[recsS_m[i] - base], 1);
    __syncthreads();
    for (int i = threadIdx.x; i < lim; i += blockDim.x)
        src_norm[base + i] = rsqrtf((float)max(cnt[i], 1));
}

// ---- K4: featb = bf16(feat * src_norm) — pre-scaled feature table (RNE). ----
__device__ __forceinline__ unsigned short f2bf(float x) {
    unsigned u = __float_as_uint(x);
    u += 0x7FFFu + ((u >> 16) & 1u);
    return (unsigned short)(u >> 16);
}

__global__ void convert_kernel(const float* __restrict__ feat, const float* __restrict__ src_norm,
                               unsigned short* __restrict__ featb, int total4) {
    int i = blockIdx.x * blockDim.x + threadIdx.x;
    if (i >= total4) return;
    float sn = src_norm[i >> 3];   // 8 float4s per row
    float4 f = ((const float4*)feat)[i];
    ushort4 u;
    u.x = f2bf(f.x * sn); u.y = f2bf(f.y * sn); u.z = f2bf(f.z * sn); u.w = f2bf(f.w * sn);
    ((ushort4*)featb)[i] = u;
}

// ---- K2d: reorder edges into dst-range buckets. rec = (s | dl<<17, ef_masked). ----
__global__ void reorder_dst(const int* __restrict__ src, const int* __restrict__ dst,
                            const float* __restrict__ ef, const int* __restrict__ offs,
                            uint2* __restrict__ recs, int E, int R, int chunk) {
    __shared__ int cur[RMAX];
    int j = blockIdx.x;
    for (int i = threadIdx.x; i < R; i += blockDim.x) cur[i] = offs[(size_t)i * JC + j];
    __syncthreads();
    int e0 = j * chunk, e1 = min(E, e0 + chunk);
    for (int e = e0 + threadIdx.x; e < e1; e += blockDim.x) {
        int s = src[e], d = dst[e];
        int r = d >> 7;
        int dl = d & (RANGE - 1);
        float w = (s == d) ? 0.0f : ef[e];
        int pos = atomicAdd(&cur[r], 1);  // LDS atomic
        recs[pos] = make_uint2((unsigned)s | ((unsigned)dl << 17), __float_as_uint(w));
    }
}

// ---- K5: per-range counting sort in LDS + per-node register gather + output. ----
__global__ __launch_bounds__(512) void gather_kernel(
        const float* __restrict__ feat, const unsigned short* __restrict__ featb,
        const uint2* __restrict__ recs, const int* __restrict__ offs,
        float* __restrict__ out, int E, int n, int R) {
    __shared__ uint2 srec[CAP];          // 20.5 KB sorted records
    __shared__ int indeg[RANGE];
    __shared__ int pre[RANGE + 1];
    __shared__ int cur[RANGE];
    int r = blockIdx.x;
    int base = r * RANGE;
    int lim = min(n - base, RANGE);
    int start = offs[(size_t)r * JC];
    int end = (r + 1 < R) ? offs[(size_t)(r + 1) * JC] : E;
    int capEnd = min(end, start + CAP);
    for (int i = threadIdx.x; i < RANGE; i += blockDim.x) indeg[i] = 0;
    __syncthreads();
    // pass 1: count per-node
    for (int i = start + threadIdx.x; i < capEnd; i += blockDim.x)
        atomicAdd(&indeg[(recs[i].x >> 17) & 0x1FFu], 1);
    __syncthreads();
    // serial exclusive scan over 128 entries (cheap)
    if (threadIdx.x == 0) {
        int run = 0;
        for (int i = 0; i < RANGE; i++) { pre[i] = run; run += indeg[i]; }
        pre[RANGE] = run;
    }
    __syncthreads();
    for (int i = threadIdx.x; i < RANGE; i += blockDim.x) cur[i] = pre[i];
    __syncthreads();
    // pass 2: place into sorted LDS buffer (re-read is L2-hot)
    for (int i = start + threadIdx.x; i < capEnd; i += blockDim.x) {
        uint2 rec = recs[i];
        int dl = (rec.x >> 17) & 0x1FFu;
        int pos = atomicAdd(&cur[dl], 1);
        srec[pos] = make_uint2(rec.x & 0x1FFFFu, rec.y);
    }
    __syncthreads();
    // gather: 4 lanes per node, 16B bf16 chunks, register accumulation
    int node = threadIdx.x >> 2;
    int c = threadIdx.x & 3;
    if (node >= lim) return;
    int p0i = pre[node];
    int cnt = pre[node + 1] - p0i;
    float a0 = 0.f, a1 = 0.f, a2 = 0.f, a3 = 0.f, a4 = 0.f, a5 = 0.f, a6 = 0.f, a7 = 0.f;
    int i = 0;
    for (; i + 2 <= cnt; i += 2) {
        uint2 q0 = srec[p0i + i];
        uint2 q1 = srec[p0i + i + 1];
        uint4 b0 = ((const uint4*)(featb + (size_t)q0.x * D))[c];
        uint4 b1 = ((const uint4*)(featb + (size_t)q1.x * D))[c];
        float w0 = __uint_as_float(q0.y);
        float w1 = __uint_as_float(q1.y);
        a0 += __uint_as_float(b0.x << 16) * w0 + __uint_as_float(b1.x << 16) * w1;
        a1 += __uint_as_float(b0.x & 0xFFFF0000u) * w0 + __uint_as_float(b1.x & 0xFFFF0000u) * w1;
        a2 += __uint_as_float(b0.y << 16) * w0 + __uint_as_float(b1.y << 16) * w1;
        a3 += __uint_as_float(b0.y & 0xFFFF0000u) * w0 + __uint_as_float(b1.y & 0xFFFF0000u) * w1;
        a4 += __uint_as_float(b0.z << 16) * w0 + __uint_as_float(b1.z << 16) * w1;
        a5 += __uint_as_float(b0.z & 0xFFFF0000u) * w0 + __uint_as_float(b1.z & 0xFFFF0000u) * w1;
        a6 += __uint_as_float(b0.w << 16) * w0 + __uint_as_float(b1.w << 16) * w1;
        a7 += __uint_as_float(b0.w & 0xFFFF0000u) * w0 + __uint_as_float(b1.w & 0xFFFF0000u) * w1;
    }
    if (i < cnt) {
        uint2 q = srec[p0i + i];
        uint4 b = ((const uint4*)(featb + (size_t)q.x * D))[c];
        float w = __uint_as_float(q.y);
        a0 += __uint_as_float(b.x << 16) * w;
        a1 += __uint_as_float(b.x & 0xFFFF0000u) * w;
        a2 += __uint_as_float(b.y << 16) * w;
        a3 += __uint_as_float(b.y & 0xFFFF0000u) * w;
        a4 += __uint_as_float(b.z << 16) * w;
        a5 += __uint_as_float(b.z & 0xFFFF0000u) * w;
        a6 += __uint_as_float(b.w << 16) * w;
        a7 += __uint_as_float(b.w & 0xFFFF0000u) * w;
    }
    // overflow fallback (statistically never taken; needed for correctness guarantee)
    if (end - start > CAP) {
        for (int k = start + CAP; k < end; k++) {
            uint2 rec = recs[k];
            int dl = (rec.x >> 17) & 0x1FFu;
            if (dl == node) {
                cnt++;
                uint4 b = ((const uint4*)(featb + (size_t)(rec.x & 0x1FFFFu) * D))[c];
                float w = __uint_as_float(rec.y);
                a0 += __uint_as_float(b.x << 16) * w;
                a1 += __uint_as_float(b.x & 0xFFFF0000u) * w;
                a2 += __uint_as_float(b.y << 16) * w;
                a3 += __uint_as_float(b.y & 0xFFFF0000u) * w;
                a4 += __uint_as_float(b.z << 16) * w;
                a5 += __uint_as_float(b.z & 0xFFFF0000u) * w;
                a6 += __uint_as_float(b.w << 16) * w;
                a7 += __uint_as_float(b.w & 0xFFFF0000u) * w;
            }
        }
    }
    float dn = rsqrtf((float)max(cnt, 1));
    const float4* fr = (const float4*)(feat + (size_t)(base + node) * D);
    float4 fA = fr[c * 2];
    float4 fB = fr[c * 2 + 1];
    float v = fabsf(fA.x - a0 * dn) + fabsf(fA.y - a1 * dn) +
              fabsf(fA.z - a2 * dn) + fabsf(fA.w - a3 * dn) +
              fabsf(fB.x - a4 * dn) + fabsf(fB.y - a5 * dn) +
              fabsf(fB.z - a6 * dn) + fabsf(fB.w - a7 * dn);
    v += __shfl_xor(v, 1, 4);
    v += __shfl_xor(v, 2, 4);
    if (c == 0) out[base + node] = v;
}

extern "C" void kernel_launch(void* const* d_in, const int* in_sizes, int n_in,
                              void* d_out, int out_size, void* d_ws, size_t ws_size,
                              hipStream_t stream) {
    const float* feat   = (const float*)d_in[0];
    const float* e_feat = (const float*)d_in[1];
    const int*   src    = (const int*)d_in[2];
    const int*   dst    = (const int*)d_in[3];
    const int E = in_sizes[2];
    const int n = in_sizes[0] / D;
    float* out = (float*)d_out;

    const int R = (n + RANGE - 1) / RANGE;   // 782
    const int chunk = (E + JC - 1) / JC;     // 3125
    const int total = 2 * R * JC;            // 800768 counts

    // ws layout (16B-aligned):
    //   offs[total] int | blockSums[256] int | src_norm[n] float |
    //   recs[E] uint2 (12.8MB; head aliases cnt[total] — cnt dead after scan) |
    //   featb[n*D] u16 (6.4MB; aliases recsS[E] u32 — recsS dead after srcnorm)
    char* p = (char*)d_ws;
    int* offs      = (int*)p;   p += ((size_t)total * 4 + 15) & ~(size_t)15;
    int* blockSums = (int*)p;   p += 256 * 4;
    float* src_norm = (float*)p; p += ((size_t)n * 4 + 15) & ~(size_t)15;
    uint2* recs    = (uint2*)p;  p += ((size_t)E * 8 + 15) & ~(size_t)15;
    int* cnt       = (int*)recs;                          // alias
    unsigned short* featb = (unsigned short*)p;
    unsigned int* recsS_m = (unsigned int*)featb - (size_t)E;  // index with [E,2E)

    count_kernel<<<JC, 256, 0, stream>>>(src, dst, cnt, E, R, chunk);

    int nb = (total + SCAN_CHUNK - 1) / SCAN_CHUNK;  // 196 (<=256)
    scan_part<<<nb, 256, 0, stream>>>(cnt, offs, blockSums, total);
    scan_top<<<1, 256, 0, stream>>>(blockSums, nb);
    scan_add<<<(total + 255) / 256, 256, 0, stream>>>(offs, blockSums, total);

    reorder_src<<<JC, 256, 0, stream>>>(src, offs, recsS_m, E, R, chunk);
    srcnorm_kernel<<<R, 256, 0, stream>>>(recsS_m, offs, src_norm, E, n, R);

    int total4 = n * D / 4;
    convert_kernel<<<(total4 + 255) / 256, 256, 0, stream>>>(feat, src_norm, featb, total4);

    reorder_dst<<<JC, 256, 0, stream>>>(src, dst, e_feat, offs, recs, E, R, chunk);

    gather_kernel<<<R, 512, 0, stream>>>(feat, featb, recs, offs, out, E, n, R);
}

// Round 8
// 172.408 us; speedup vs baseline: 2.3827x; 1.0262x over previous
//
#include <hip/hip_runtime.h>

#define D 32
#define RANGE 128        // nodes per range; R = ceil(n/RANGE) = 782
#define RMAX 800         // LDS counter capacity for coarse passes
#define JC 512           // edge chunks for count/reorder passes
#define SCAN_CHUNK 4096  // scan: 256 threads x 16 elems
#define CAP 2560         // LDS sorted-record capacity per range (mean 2048, +11 sigma)

// ---- K1: per-(range,chunk) coarse counts for dst AND src in one pass. ----
__global__ void count_kernel(const int* __restrict__ src, const int* __restrict__ dst,
                             int* __restrict__ cnt, int E, int R, int chunk) {
    __shared__ int cd[RMAX];
    __shared__ int cs[RMAX];
    int j = blockIdx.x;
    for (int i = threadIdx.x; i < R; i += blockDim.x) { cd[i] = 0; cs[i] = 0; }
    __syncthreads();
    int e0 = j * chunk, e1 = min(E, e0 + chunk);
    for (int e = e0 + threadIdx.x; e < e1; e += blockDim.x) {
        atomicAdd(&cd[dst[e] >> 7], 1);   // RANGE = 128
        atomicAdd(&cs[src[e] >> 7], 1);
    }
    __syncthreads();
    // layout: cnt[r*JC + j] (dst) ; cnt[(R+r)*JC + j] (src)
    for (int i = threadIdx.x; i < R; i += blockDim.x) {
        cnt[(size_t)i * JC + j]       = cd[i];
        cnt[(size_t)(R + i) * JC + j] = cs[i];
    }
}

// ---- hierarchical exclusive scan over 2*R*JC counts ----
__global__ void scan_part(const int* __restrict__ deg, int* __restrict__ offsets,
                          int* __restrict__ blockSums, int n) {
    __shared__ int lds[256];
    int t = threadIdx.x;
    int base = blockIdx.x * SCAN_CHUNK + t * 16;
    int v[16];
    int tsum = 0;
#pragma unroll
    for (int i = 0; i < 16; i++) {
        int idx = base + i;
        int x = (idx < n) ? deg[idx] : 0;
        v[i] = tsum;
        tsum += x;
    }
    lds[t] = tsum;
    __syncthreads();
    for (int off = 1; off < 256; off <<= 1) {
        int val = (t >= off) ? lds[t - off] : 0;
        __syncthreads();
        lds[t] += val;
        __syncthreads();
    }
    int texcl = (t == 0) ? 0 : lds[t - 1];
    if (t == 255) blockSums[blockIdx.x] = lds[255];
#pragma unroll
    for (int i = 0; i < 16; i++) {
        int idx = base + i;
        if (idx < n) offsets[idx] = texcl + v[i];
    }
}

__global__ void scan_top(int* __restrict__ blockSums, int nb) {
    __shared__ int lds[256];
    int t = threadIdx.x;
    lds[t] = (t < nb) ? blockSums[t] : 0;
    __syncthreads();
    for (int off = 1; off < 256; off <<= 1) {
        int val = (t >= off) ? lds[t - off] : 0;
        __syncthreads();
        lds[t] += val;
        __syncthreads();
    }
    if (t < nb) blockSums[t] = (t == 0) ? 0 : lds[t - 1];
}

__global__ void scan_add(int* __restrict__ offsets, const int* __restrict__ blockSums, int n) {
    int i = blockIdx.x * blockDim.x + threadIdx.x;
    if (i < n) offsets[i] += blockSums[i / SCAN_CHUNK];
}

// ---- K2: fused reorder — one pass over edges writes BOTH bucketed streams. ----
// dst stream: recs = (s | dl<<17, ef_masked). src stream: recsS = s (4B).
// recsS_m is pre-offset by -E so src-bucket offsets in [E,2E) index [0,E).
__global__ void reorder_kernel(const int* __restrict__ src, const int* __restrict__ dst,
                               const float* __restrict__ ef, const int* __restrict__ offs,
                               unsigned int* __restrict__ recsS_m, uint2* __restrict__ recs,
                               int E, int R, int chunk) {
    __shared__ int curD[RMAX];
    __shared__ int curS[RMAX];
    int j = blockIdx.x;
    for (int i = threadIdx.x; i < R; i += blockDim.x) {
        curD[i] = offs[(size_t)i * JC + j];
        curS[i] = offs[(size_t)(R + i) * JC + j];
    }
    __syncthreads();
    int e0 = j * chunk, e1 = min(E, e0 + chunk);
    for (int e = e0 + threadIdx.x; e < e1; e += blockDim.x) {
        int s = src[e], d = dst[e];
        int ps = atomicAdd(&curS[s >> 7], 1);          // LDS atomic
        recsS_m[ps] = (unsigned)s;
        float w = (s == d) ? 0.0f : ef[e];
        int pd = atomicAdd(&curD[d >> 7], 1);          // LDS atomic
        recs[pd] = make_uint2((unsigned)s | ((unsigned)(d & (RANGE - 1)) << 17),
                              __float_as_uint(w));
    }
}

// ---- K3: fused out-degree count + pre-scaled bf16 feature rows for the range. ----
__device__ __forceinline__ unsigned short f2bf(float x) {
    unsigned u = __float_as_uint(x);
    u += 0x7FFFu + ((u >> 16) & 1u);
    return (unsigned short)(u >> 16);
}

__global__ void srcnorm_convert(const unsigned int* __restrict__ recsS_m,
                                const int* __restrict__ offs, const float* __restrict__ feat,
                                unsigned short* __restrict__ featb, int E, int n, int R) {
    __shared__ int cnt[RANGE];
    int r = blockIdx.x;
    int base = r * RANGE;
    int lim = min(n - base, RANGE);
    for (int i = threadIdx.x; i < RANGE; i += blockDim.x) cnt[i] = 0;
    __syncthreads();
    int start = offs[(size_t)(R + r) * JC];
    int end = (r + 1 < R) ? offs[(size_t)(R + r + 1) * JC] : 2 * E;
    for (int i = start + threadIdx.x; i < end; i += blockDim.x)
        atomicAdd(&cnt[recsS_m[i] - base], 1);         // LDS atomic
    __syncthreads();
    int total4 = lim * 8;   // 8 float4 chunks per row
    for (int i = threadIdx.x; i < total4; i += blockDim.x) {
        int row = i >> 3;
        float sn = rsqrtf((float)max(cnt[row], 1));
        float4 f = ((const float4*)(feat + (size_t)(base + row) * D))[i & 7];
        ushort4 u;
        u.x = f2bf(f.x * sn); u.y = f2bf(f.y * sn);
        u.z = f2bf(f.z * sn); u.w = f2bf(f.w * sn);
        ((ushort4*)(featb + (size_t)(base + row) * D))[i & 7] = u;
    }
}

// ---- K4: per-range counting sort in LDS + per-node register gather + output. ----
__global__ __launch_bounds__(512) void gather_kernel(
        const float* __restrict__ feat, const unsigned short* __restrict__ featb,
        const uint2* __restrict__ recs, const int* __restrict__ offs,
        float* __restrict__ out, int E, int n, int R) {
    __shared__ uint2 srec[CAP];          // 20.5 KB sorted records
    __shared__ int indeg[RANGE];
    __shared__ int pre[RANGE + 1];
    __shared__ int cur[RANGE];
    int r = blockIdx.x;
    int base = r * RANGE;
    int lim = min(n - base, RANGE);
    int start = offs[(size_t)r * JC];
    int end = (r + 1 < R) ? offs[(size_t)(r + 1) * JC] : E;
    int capEnd = min(end, start + CAP);
    for (int i = threadIdx.x; i < RANGE; i += blockDim.x) indeg[i] = 0;
    __syncthreads();
    // pass 1: count per-node
    for (int i = start + threadIdx.x; i < capEnd; i += blockDim.x)
        atomicAdd(&indeg[(recs[i].x >> 17) & 0x1FFu], 1);
    __syncthreads();
    // parallel Hillis-Steele inclusive scan -> pre[1..RANGE], pre[0]=0
    if (threadIdx.x < RANGE) pre[threadIdx.x + 1] = indeg[threadIdx.x];
    if (threadIdx.x == 0) pre[0] = 0;
    __syncthreads();
    for (int off = 1; off < RANGE; off <<= 1) {
        int v = 0;
        if (threadIdx.x < RANGE) {
            int idx = threadIdx.x + 1;
            if (idx > off) v = pre[idx - off];
        }
        __syncthreads();
        if (threadIdx.x < RANGE) pre[threadIdx.x + 1] += v;
        __syncthreads();
    }
    if (threadIdx.x < RANGE) cur[threadIdx.x] = pre[threadIdx.x];
    __syncthreads();
    // pass 2: place into sorted LDS buffer (re-read is L2-hot)
    for (int i = start + threadIdx.x; i < capEnd; i += blockDim.x) {
        uint2 rec = recs[i];
        int dl = (rec.x >> 17) & 0x1FFu;
        int pos = atomicAdd(&cur[dl], 1);
        srec[pos] = make_uint2(rec.x & 0x1FFFFu, rec.y);
    }
    __syncthreads();
    // gather: 4 lanes per node, 16B bf16 chunks, register accumulation
    int node = threadIdx.x >> 2;
    int c = threadIdx.x & 3;
    if (node >= lim) return;
    int p0i = pre[node];
    int cnt = pre[node + 1] - p0i;
    float a0 = 0.f, a1 = 0.f, a2 = 0.f, a3 = 0.f, a4 = 0.f, a5 = 0.f, a6 = 0.f, a7 = 0.f;
    int i = 0;
    for (; i + 2 <= cnt; i += 2) {
        uint2 q0 = srec[p0i + i];
        uint2 q1 = srec[p0i + i + 1];
        uint4 b0 = ((const uint4*)(featb + (size_t)q0.x * D))[c];
        uint4 b1 = ((const uint4*)(featb + (size_t)q1.x * D))[c];
        float w0 = __uint_as_float(q0.y);
        float w1 = __uint_as_float(q1.y);
        a0 += __uint_as_float(b0.x << 16) * w0 + __uint_as_float(b1.x << 16) * w1;
        a1 += __uint_as_float(b0.x & 0xFFFF0000u) * w0 + __uint_as_float(b1.x & 0xFFFF0000u) * w1;
        a2 += __uint_as_float(b0.y << 16) * w0 + __uint_as_float(b1.y << 16) * w1;
        a3 += __uint_as_float(b0.y & 0xFFFF0000u) * w0 + __uint_as_float(b1.y & 0xFFFF0000u) * w1;
        a4 += __uint_as_float(b0.z << 16) * w0 + __uint_as_float(b1.z << 16) * w1;
        a5 += __uint_as_float(b0.z & 0xFFFF0000u) * w0 + __uint_as_float(b1.z & 0xFFFF0000u) * w1;
        a6 += __uint_as_float(b0.w << 16) * w0 + __uint_as_float(b1.w << 16) * w1;
        a7 += __uint_as_float(b0.w & 0xFFFF0000u) * w0 + __uint_as_float(b1.w & 0xFFFF0000u) * w1;
    }
    if (i < cnt) {
        uint2 q = srec[p0i + i];
        uint4 b = ((const uint4*)(featb + (size_t)q.x * D))[c];
        float w = __uint_as_float(q.y);
        a0 += __uint_as_float(b.x << 16) * w;
        a1 += __uint_as_float(b.x & 0xFFFF0000u) * w;
        a2 += __uint_as_float(b.y << 16) * w;
        a3 += __uint_as_float(b.y & 0xFFFF0000u) * w;
        a4 += __uint_as_float(b.z << 16) * w;
        a5 += __uint_as_float(b.z & 0xFFFF0000u) * w;
        a6 += __uint_as_float(b.w << 16) * w;
        a7 += __uint_as_float(b.w & 0xFFFF0000u) * w;
    }
    // overflow fallback (statistically never taken; needed for correctness guarantee)
    if (end - start > CAP) {
        for (int k = start + CAP; k < end; k++) {
            uint2 rec = recs[k];
            int dl = (rec.x >> 17) & 0x1FFu;
            if (dl == node) {
                cnt++;
                uint4 b = ((const uint4*)(featb + (size_t)(rec.x & 0x1FFFFu) * D))[c];
                float w = __uint_as_float(rec.y);
                a0 += __uint_as_float(b.x << 16) * w;
                a1 += __uint_as_float(b.x & 0xFFFF0000u) * w;
                a2 += __uint_as_float(b.y << 16) * w;
                a3 += __uint_as_float(b.y & 0xFFFF0000u) * w;
                a4 += __uint_as_float(b.z << 16) * w;
                a5 += __uint_as_float(b.z & 0xFFFF0000u) * w;
                a6 += __uint_as_float(b.w << 16) * w;
                a7 += __uint_as_float(b.w & 0xFFFF0000u) * w;
            }
        }
    }
    float dn = rsqrtf((float)max(cnt, 1));
    const float4* fr = (const float4*)(feat + (size_t)(base + node) * D);
    float4 fA = fr[c * 2];
    float4 fB = fr[c * 2 + 1];
    float v = fabsf(fA.x - a0 * dn) + fabsf(fA.y - a1 * dn) +
              fabsf(fA.z - a2 * dn) + fabsf(fA.w - a3 * dn) +
              fabsf(fB.x - a4 * dn) + fabsf(fB.y - a5 * dn) +
              fabsf(fB.z - a6 * dn) + fabsf(fB.w - a7 * dn);
    v += __shfl_xor(v, 1, 4);
    v += __shfl_xor(v, 2, 4);
    if (c == 0) out[base + node] = v;
}

extern "C" void kernel_launch(void* const* d_in, const int* in_sizes, int n_in,
                              void* d_out, int out_size, void* d_ws, size_t ws_size,
                              hipStream_t stream) {
    const float* feat   = (const float*)d_in[0];
    const float* e_feat = (const float*)d_in[1];
    const int*   src    = (const int*)d_in[2];
    const int*   dst    = (const int*)d_in[3];
    const int E = in_sizes[2];
    const int n = in_sizes[0] / D;
    float* out = (float*)d_out;

    const int R = (n + RANGE - 1) / RANGE;   // 782
    const int chunk = (E + JC - 1) / JC;     // 3125
    const int total = 2 * R * JC;            // 800768 counts

    // ws layout (16B-aligned, no aliasing — ws is 256MB, we use ~32MB):
    //   cnt[total] int | offs[total] int | blockSums[256] int |
    //   recs[E] uint2 | recsS[E] uint | featb[n*D] ushort
    char* p = (char*)d_ws;
    int* cnt       = (int*)p;   p += ((size_t)total * 4 + 15) & ~(size_t)15;
    int* offs      = (int*)p;   p += ((size_t)total * 4 + 15) & ~(size_t)15;
    int* blockSums = (int*)p;   p += 256 * 4;
    uint2* recs    = (uint2*)p; p += ((size_t)E * 8 + 15) & ~(size_t)15;
    unsigned int* recsS = (unsigned int*)p; p += ((size_t)E * 4 + 15) & ~(size_t)15;
    unsigned short* featb = (unsigned short*)p;
    unsigned int* recsS_m = recsS - (size_t)E;   // index with [E, 2E)

    count_kernel<<<JC, 256, 0, stream>>>(src, dst, cnt, E, R, chunk);

    int nb = (total + SCAN_CHUNK - 1) / SCAN_CHUNK;  // 196 (<=256)
    scan_part<<<nb, 256, 0, stream>>>(cnt, offs, blockSums, total);
    scan_top<<<1, 256, 0, stream>>>(blockSums, nb);
    scan_add<<<(total + 255) / 256, 256, 0, stream>>>(offs, blockSums, total);

    reorder_kernel<<<JC, 256, 0, stream>>>(src, dst, e_feat, offs, recsS_m, recs, E, R, chunk);

    srcnorm_convert<<<R, 256, 0, stream>>>(recsS_m, offs, feat, featb, E, n, R);

    gather_kernel<<<R, 512, 0, stream>>>(feat, featb, recs, offs, out, E, n, R);
}

// Round 9
// 163.962 us; speedup vs baseline: 2.5055x; 1.0515x over previous
//
#include <hip/hip_runtime.h>

#define D 32
#define RANGE 128        // nodes per range; R = ceil(n/RANGE) = 782
#define RMAX 800         // LDS counter capacity for coarse passes
#define JC 512           // edge chunks for count/reorder passes
#define SCAN_CHUNK 4096  // scan: 256 threads x 16 elems
#define CAP 2560         // LDS sorted-record capacity per range (mean 2048, +11 sigma)

// ---- K1: per-(range,chunk) coarse counts for dst AND src in one pass. ----
__global__ __launch_bounds__(512) void count_kernel(
        const int* __restrict__ src, const int* __restrict__ dst,
        int* __restrict__ cnt, int E, int R, int chunk) {
    __shared__ int cd[RMAX];
    __shared__ int cs[RMAX];
    int j = blockIdx.x;
    for (int i = threadIdx.x; i < R; i += blockDim.x) { cd[i] = 0; cs[i] = 0; }
    __syncthreads();
    int e0 = j * chunk, e1 = min(E, e0 + chunk);
    for (int e = e0 + 2 * threadIdx.x; e < e1; e += 2 * blockDim.x) {
        if (e + 1 < e1) {
            int2 s2 = *(const int2*)(src + e);
            int2 d2 = *(const int2*)(dst + e);
            atomicAdd(&cd[d2.x >> 7], 1);
            atomicAdd(&cd[d2.y >> 7], 1);
            atomicAdd(&cs[s2.x >> 7], 1);
            atomicAdd(&cs[s2.y >> 7], 1);
        } else {
            atomicAdd(&cd[dst[e] >> 7], 1);
            atomicAdd(&cs[src[e] >> 7], 1);
        }
    }
    __syncthreads();
    // layout: cnt[r*JC + j] (dst) ; cnt[(R+r)*JC + j] (src)
    for (int i = threadIdx.x; i < R; i += blockDim.x) {
        cnt[(size_t)i * JC + j]       = cd[i];
        cnt[(size_t)(R + i) * JC + j] = cs[i];
    }
}

// ---- hierarchical exclusive scan over 2*R*JC counts ----
__global__ void scan_part(const int* __restrict__ deg, int* __restrict__ offsets,
                          int* __restrict__ blockSums, int n) {
    __shared__ int lds[256];
    int t = threadIdx.x;
    int base = blockIdx.x * SCAN_CHUNK + t * 16;
    int v[16];
    int tsum = 0;
#pragma unroll
    for (int i = 0; i < 16; i++) {
        int idx = base + i;
        int x = (idx < n) ? deg[idx] : 0;
        v[i] = tsum;
        tsum += x;
    }
    lds[t] = tsum;
    __syncthreads();
    for (int off = 1; off < 256; off <<= 1) {
        int val = (t >= off) ? lds[t - off] : 0;
        __syncthreads();
        lds[t] += val;
        __syncthreads();
    }
    int texcl = (t == 0) ? 0 : lds[t - 1];
    if (t == 255) blockSums[blockIdx.x] = lds[255];
#pragma unroll
    for (int i = 0; i < 16; i++) {
        int idx = base + i;
        if (idx < n) offsets[idx] = texcl + v[i];
    }
}

__global__ void scan_top(int* __restrict__ blockSums, int nb) {
    __shared__ int lds[256];
    int t = threadIdx.x;
    lds[t] = (t < nb) ? blockSums[t] : 0;
    __syncthreads();
    for (int off = 1; off < 256; off <<= 1) {
        int val = (t >= off) ? lds[t - off] : 0;
        __syncthreads();
        lds[t] += val;
        __syncthreads();
    }
    if (t < nb) blockSums[t] = (t == 0) ? 0 : lds[t - 1];
}

__global__ void scan_add(int* __restrict__ offsets, const int* __restrict__ blockSums, int n) {
    int i = blockIdx.x * blockDim.x + threadIdx.x;
    if (i < n) offsets[i] += blockSums[i / SCAN_CHUNK];
}

// ---- K2: fused reorder — one pass over edges writes BOTH bucketed streams. ----
// dst stream: recs = (s | dl<<17, ef_masked). src stream: recsS = s (4B).
// recsS_m is pre-offset by -E so src-bucket offsets in [E,2E) index [0,E).
__global__ __launch_bounds__(512) void reorder_kernel(
        const int* __restrict__ src, const int* __restrict__ dst,
        const float* __restrict__ ef, const int* __restrict__ offs,
        unsigned int* __restrict__ recsS_m, uint2* __restrict__ recs,
        int E, int R, int chunk) {
    __shared__ int curD[RMAX];
    __shared__ int curS[RMAX];
    int j = blockIdx.x;
    for (int i = threadIdx.x; i < R; i += blockDim.x) {
        curD[i] = offs[(size_t)i * JC + j];
        curS[i] = offs[(size_t)(R + i) * JC + j];
    }
    __syncthreads();
    int e0 = j * chunk, e1 = min(E, e0 + chunk);
    for (int e = e0 + 2 * threadIdx.x; e < e1; e += 2 * blockDim.x) {
        if (e + 1 < e1) {
            int2 s2 = *(const int2*)(src + e);
            int2 d2 = *(const int2*)(dst + e);
            float2 w2 = *(const float2*)(ef + e);
            int ps0 = atomicAdd(&curS[s2.x >> 7], 1);
            int ps1 = atomicAdd(&curS[s2.y >> 7], 1);
            recsS_m[ps0] = (unsigned)s2.x;
            recsS_m[ps1] = (unsigned)s2.y;
            float w0 = (s2.x == d2.x) ? 0.0f : w2.x;
            float w1 = (s2.y == d2.y) ? 0.0f : w2.y;
            int pd0 = atomicAdd(&curD[d2.x >> 7], 1);
            int pd1 = atomicAdd(&curD[d2.y >> 7], 1);
            recs[pd0] = make_uint2((unsigned)s2.x | ((unsigned)(d2.x & (RANGE - 1)) << 17),
                                   __float_as_uint(w0));
            recs[pd1] = make_uint2((unsigned)s2.y | ((unsigned)(d2.y & (RANGE - 1)) << 17),
                                   __float_as_uint(w1));
        } else {
            int s = src[e], d = dst[e];
            int ps = atomicAdd(&curS[s >> 7], 1);
            recsS_m[ps] = (unsigned)s;
            float w = (s == d) ? 0.0f : ef[e];
            int pd = atomicAdd(&curD[d >> 7], 1);
            recs[pd] = make_uint2((unsigned)s | ((unsigned)(d & (RANGE - 1)) << 17),
                                  __float_as_uint(w));
        }
    }
}

// ---- K3: fused out-degree count + pre-scaled bf16 feature rows for the range. ----
__device__ __forceinline__ unsigned short f2bf(float x) {
    unsigned u = __float_as_uint(x);
    u += 0x7FFFu + ((u >> 16) & 1u);
    return (unsigned short)(u >> 16);
}

__global__ void srcnorm_convert(const unsigned int* __restrict__ recsS_m,
                                const int* __restrict__ offs, const float* __restrict__ feat,
                                unsigned short* __restrict__ featb, int E, int n, int R) {
    __shared__ int cnt[RANGE];
    int r = blockIdx.x;
    int base = r * RANGE;
    int lim = min(n - base, RANGE);
    for (int i = threadIdx.x; i < RANGE; i += blockDim.x) cnt[i] = 0;
    __syncthreads();
    int start = offs[(size_t)(R + r) * JC];
    int end = (r + 1 < R) ? offs[(size_t)(R + r + 1) * JC] : 2 * E;
    for (int i = start + threadIdx.x; i < end; i += blockDim.x)
        atomicAdd(&cnt[recsS_m[i] - base], 1);         // LDS atomic
    __syncthreads();
    int total4 = lim * 8;   // 8 float4 chunks per row
    for (int i = threadIdx.x; i < total4; i += blockDim.x) {
        int row = i >> 3;
        float sn = rsqrtf((float)max(cnt[row], 1));
        float4 f = ((const float4*)(feat + (size_t)(base + row) * D))[i & 7];
        ushort4 u;
        u.x = f2bf(f.x * sn); u.y = f2bf(f.y * sn);
        u.z = f2bf(f.z * sn); u.w = f2bf(f.w * sn);
        ((ushort4*)(featb + (size_t)(base + row) * D))[i & 7] = u;
    }
}

// ---- K4: per-range counting sort in LDS + per-node register gather + output. ----
__global__ __launch_bounds__(512) void gather_kernel(
        const float* __restrict__ feat, const unsigned short* __restrict__ featb,
        const uint2* __restrict__ recs, const int* __restrict__ offs,
        float* __restrict__ out, int E, int n, int R) {
    __shared__ uint2 srec[CAP];          // 20.5 KB sorted records
    __shared__ int indeg[RANGE];
    __shared__ int pre[RANGE + 1];
    __shared__ int cur[RANGE];
    int r = blockIdx.x;
    int base = r * RANGE;
    int lim = min(n - base, RANGE);
    int start = offs[(size_t)r * JC];
    int end = (r + 1 < R) ? offs[(size_t)(r + 1) * JC] : E;
    int capEnd = min(end, start + CAP);
    for (int i = threadIdx.x; i < RANGE; i += blockDim.x) indeg[i] = 0;
    __syncthreads();
    // pass 1: count per-node
    for (int i = start + threadIdx.x; i < capEnd; i += blockDim.x)
        atomicAdd(&indeg[(recs[i].x >> 17) & 0x1FFu], 1);
    __syncthreads();
    // parallel Hillis-Steele inclusive scan -> pre[1..RANGE], pre[0]=0
    if (threadIdx.x < RANGE) pre[threadIdx.x + 1] = indeg[threadIdx.x];
    if (threadIdx.x == 0) pre[0] = 0;
    __syncthreads();
    for (int off = 1; off < RANGE; off <<= 1) {
        int v = 0;
        if (threadIdx.x < RANGE) {
            int idx = threadIdx.x + 1;
            if (idx > off) v = pre[idx - off];
        }
        __syncthreads();
        if (threadIdx.x < RANGE) pre[threadIdx.x + 1] += v;
        __syncthreads();
    }
    if (threadIdx.x < RANGE) cur[threadIdx.x] = pre[threadIdx.x];
    __syncthreads();
    // pass 2: place into sorted LDS buffer (re-read is L2-hot)
    for (int i = start + threadIdx.x; i < capEnd; i += blockDim.x) {
        uint2 rec = recs[i];
        int dl = (rec.x >> 17) & 0x1FFu;
        int pos = atomicAdd(&cur[dl], 1);
        srec[pos] = make_uint2(rec.x & 0x1FFFFu, rec.y);
    }
    __syncthreads();
    // gather: 4 lanes per node, 16B bf16 chunks, register accumulation
    int node = threadIdx.x >> 2;
    int c = threadIdx.x & 3;
    if (node >= lim) return;
    int p0i = pre[node];
    int cnt = pre[node + 1] - p0i;
    float a0 = 0.f, a1 = 0.f, a2 = 0.f, a3 = 0.f, a4 = 0.f, a5 = 0.f, a6 = 0.f, a7 = 0.f;
    int i = 0;
    for (; i + 2 <= cnt; i += 2) {
        uint2 q0 = srec[p0i + i];
        uint2 q1 = srec[p0i + i + 1];
        uint4 b0 = ((const uint4*)(featb + (size_t)q0.x * D))[c];
        uint4 b1 = ((const uint4*)(featb + (size_t)q1.x * D))[c];
        float w0 = __uint_as_float(q0.y);
        float w1 = __uint_as_float(q1.y);
        a0 += __uint_as_float(b0.x << 16) * w0 + __uint_as_float(b1.x << 16) * w1;
        a1 += __uint_as_float(b0.x & 0xFFFF0000u) * w0 + __uint_as_float(b1.x & 0xFFFF0000u) * w1;
        a2 += __uint_as_float(b0.y << 16) * w0 + __uint_as_float(b1.y << 16) * w1;
        a3 += __uint_as_float(b0.y & 0xFFFF0000u) * w0 + __uint_as_float(b1.y & 0xFFFF0000u) * w1;
        a4 += __uint_as_float(b0.z << 16) * w0 + __uint_as_float(b1.z << 16) * w1;
        a5 += __uint_as_float(b0.z & 0xFFFF0000u) * w0 + __uint_as_float(b1.z & 0xFFFF0000u) * w1;
        a6 += __uint_as_float(b0.w << 16) * w0 + __uint_as_float(b1.w << 16) * w1;
        a7 += __uint_as_float(b0.w & 0xFFFF0000u) * w0 + __uint_as_float(b1.w & 0xFFFF0000u) * w1;
    }
    if (i < cnt) {
        uint2 q = srec[p0i + i];
        uint4 b = ((const uint4*)(featb + (size_t)q.x * D))[c];
        float w = __uint_as_float(q.y);
        a0 += __uint_as_float(b.x << 16) * w;
        a1 += __uint_as_float(b.x & 0xFFFF0000u) * w;
        a2 += __uint_as_float(b.y << 16) * w;
        a3 += __uint_as_float(b.y & 0xFFFF0000u) * w;
        a4 += __uint_as_float(b.z << 16) * w;
        a5 += __uint_as_float(b.z & 0xFFFF0000u) * w;
        a6 += __uint_as_float(b.w << 16) * w;
        a7 += __uint_as_float(b.w & 0xFFFF0000u) * w;
    }
    // overflow fallback (statistically never taken; needed for correctness guarantee)
    if (end - start > CAP) {
        for (int k = start + CAP; k < end; k++) {
            uint2 rec = recs[k];
            int dl = (rec.x >> 17) & 0x1FFu;
            if (dl == node) {
                cnt++;
                uint4 b = ((const uint4*)(featb + (size_t)(rec.x & 0x1FFFFu) * D))[c];
                float w = __uint_as_float(rec.y);
                a0 += __uint_as_float(b.x << 16) * w;
                a1 += __uint_as_float(b.x & 0xFFFF0000u) * w;
                a2 += __uint_as_float(b.y << 16) * w;
                a3 += __uint_as_float(b.y & 0xFFFF0000u) * w;
                a4 += __uint_as_float(b.z << 16) * w;
                a5 += __uint_as_float(b.z & 0xFFFF0000u) * w;
                a6 += __uint_as_float(b.w << 16) * w;
                a7 += __uint_as_float(b.w & 0xFFFF0000u) * w;
            }
        }
    }
    float dn = rsqrtf((float)max(cnt, 1));
    const float4* fr = (const float4*)(feat + (size_t)(base + node) * D);
    float4 fA = fr[c * 2];
    float4 fB = fr[c * 2 + 1];
    float v = fabsf(fA.x - a0 * dn) + fabsf(fA.y - a1 * dn) +
              fabsf(fA.z - a2 * dn) + fabsf(fA.w - a3 * dn) +
              fabsf(fB.x - a4 * dn) + fabsf(fB.y - a5 * dn) +
              fabsf(fB.z - a6 * dn) + fabsf(fB.w - a7 * dn);
    v += __shfl_xor(v, 1, 4);
    v += __shfl_xor(v, 2, 4);
    if (c == 0) out[base + node] = v;
}

extern "C" void kernel_launch(void* const* d_in, const int* in_sizes, int n_in,
                              void* d_out, int out_size, void* d_ws, size_t ws_size,
                              hipStream_t stream) {
    const float* feat   = (const float*)d_in[0];
    const float* e_feat = (const float*)d_in[1];
    const int*   src    = (const int*)d_in[2];
    const int*   dst    = (const int*)d_in[3];
    const int E = in_sizes[2];
    const int n = in_sizes[0] / D;
    float* out = (float*)d_out;

    const int R = (n + RANGE - 1) / RANGE;              // 782
    const int chunk = (((E + JC - 1) / JC) + 1) & ~1;   // even chunk -> int2 pairs never split
    const int total = 2 * R * JC;                       // 800768 counts

    // ws layout (16B-aligned, no aliasing — ws is 256MB, we use ~32MB):
    //   cnt[total] int | offs[total] int | blockSums[256] int |
    //   recs[E] uint2 | recsS[E] uint | featb[n*D] ushort
    char* p = (char*)d_ws;
    int* cnt       = (int*)p;   p += ((size_t)total * 4 + 15) & ~(size_t)15;
    int* offs      = (int*)p;   p += ((size_t)total * 4 + 15) & ~(size_t)15;
    int* blockSums = (int*)p;   p += 256 * 4;
    uint2* recs    = (uint2*)p; p += ((size_t)E * 8 + 15) & ~(size_t)15;
    unsigned int* recsS = (unsigned int*)p; p += ((size_t)E * 4 + 15) & ~(size_t)15;
    unsigned short* featb = (unsigned short*)p;
    unsigned int* recsS_m = recsS - (size_t)E;   // index with [E, 2E)

    count_kernel<<<JC, 512, 0, stream>>>(src, dst, cnt, E, R, chunk);

    int nb = (total + SCAN_CHUNK - 1) / SCAN_CHUNK;  // 196 (<=256)
    scan_part<<<nb, 256, 0, stream>>>(cnt, offs, blockSums, total);
    scan_top<<<1, 256, 0, stream>>>(blockSums, nb);
    scan_add<<<(total + 255) / 256, 256, 0, stream>>>(offs, blockSums, total);

    reorder_kernel<<<JC, 512, 0, stream>>>(src, dst, e_feat, offs, recsS_m, recs, E, R, chunk);

    srcnorm_convert<<<R, 256, 0, stream>>>(recsS_m, offs, feat, featb, E, n, R);

    gather_kernel<<<R, 512, 0, stream>>>(feat, featb, recs, offs, out, E, n, R);
}